// Round 8
// baseline (254.016 us; speedup 1.0000x reference)
//
#include <hip/hip_runtime.h>
#include <stdint.h>

typedef __bf16 bf16_t;
typedef __bf16 bf16x8 __attribute__((ext_vector_type(8)));
typedef float f32x4 __attribute__((ext_vector_type(4)));

#define LOG2E 1.44269504088896340736f

__device__ __forceinline__ float fexp2(float x) {
#if __has_builtin(__builtin_amdgcn_exp2f)
    return __builtin_amdgcn_exp2f(x);   // bare v_exp_f32
#else
    return exp2f(x);
#endif
}

// ---- async global->LDS, 16B per lane. LDS dest = wave-uniform base + lane*16.
__device__ __forceinline__ void gld_lds16(const bf16_t* g, bf16_t* l) {
    __builtin_amdgcn_global_load_lds(
        (__attribute__((address_space(1))) void*)(bf16_t*)g,
        (__attribute__((address_space(3))) void*)l,
        16, 0, 0);
}

// ============================ fused prep kernel ============================
// blocks [0,8192): x f32->bf16 | [8192,11264): W_qkv transpose | [11264,12288): W_o
__global__ __launch_bounds__(256) void prep_k(
    const float* __restrict__ x, bf16_t* __restrict__ xb,
    const float* __restrict__ Wqkv, bf16_t* __restrict__ wqkvT,
    const float* __restrict__ Wo, bf16_t* __restrict__ woT)
{
    __shared__ float t[32][33];
    const int tid = threadIdx.x;
    int blk = blockIdx.x;
    if (blk < 8192) {
        int i = blk * 1024 + tid * 4;
        float4 v = *(const float4*)(x + i);
        union { bf16_t b[4]; uint2 u; } u;
        u.b[0] = (bf16_t)v.x; u.b[1] = (bf16_t)v.y; u.b[2] = (bf16_t)v.z; u.b[3] = (bf16_t)v.w;
        *(uint2*)(xb + i) = u.u;
        return;
    }
    const float* in; bf16_t* out; int C, bx, by;
    if (blk < 11264) { blk -= 8192; in = Wqkv; out = wqkvT; C = 3072; bx = blk % 96; by = blk / 96; }
    else             { blk -= 11264; in = Wo;   out = woT;   C = 1024; bx = blk % 32; by = blk / 32; }
    const int R = 1024;
    const int tx = tid & 31, ty = tid >> 5;
    const int c0 = bx * 32, r0 = by * 32;
    #pragma unroll
    for (int j = 0; j < 32; j += 8)
        t[ty + j][tx] = in[(size_t)(r0 + ty + j) * C + c0 + tx];
    __syncthreads();
    #pragma unroll
    for (int j = 0; j < 32; j += 8)
        out[(size_t)(c0 + ty + j) * R + r0 + tx] = (bf16_t)t[tx][ty + j];
}

// ============================ shared GEMM body (BK=64) ============================
// C[128x128] = A[m0:+128,:K] * B[n0:+128,:K]^T (both row-major, k-contig).
// XOR swizzle at 16B-chunk granularity. C-layout: col(l15)=n, row(quad*4+r)=m.
__device__ __forceinline__ void gemm128_body(
    const bf16_t* __restrict__ A, const bf16_t* __restrict__ Bt,
    bf16_t* Al, bf16_t* Bl, f32x4 (&acc)[4][4], int m0, int n0, int Kd)
{
    const int tid = threadIdx.x;
    const int w = tid >> 6, lane = tid & 63;
    const int l15 = lane & 15, quad = lane >> 4;
    const int wm = w >> 1, wn = w & 1;

    const int srow = lane >> 3;                 // 0..7 within an 8-row group
    const int scg = ((lane & 7) ^ srow) * 8;    // swizzled global chunk
    const bf16_t* Ag = A + (size_t)(m0 + w * 32 + srow) * Kd + scg;
    const bf16_t* Bg = Bt + (size_t)(n0 + w * 32 + srow) * Kd + scg;
    bf16_t* Ald = Al + (w * 32) * 64;
    bf16_t* Bld = Bl + (w * 32) * 64;

    const int rc0 = (quad ^ (l15 & 7)) * 8;
    const int rc1 = ((quad + 4) ^ (l15 & 7)) * 8;

    for (int k0 = 0; k0 < Kd; k0 += 64) {
        __syncthreads();
        #pragma unroll
        for (int j = 0; j < 4; j++) {
            gld_lds16(Ag + k0 + (size_t)(j * 8) * Kd, Ald + (j * 8) * 64);
            gld_lds16(Bg + k0 + (size_t)(j * 8) * Kd, Bld + (j * 8) * 64);
        }
        __syncthreads();

        #pragma unroll
        for (int hh = 0; hh < 2; hh++) {
            const int rc = hh ? rc1 : rc0;
            bf16x8 af[4], bf[4];
            #pragma unroll
            for (int mi = 0; mi < 4; mi++)
                af[mi] = *(const bf16x8*)(Al + (wm * 64 + mi * 16 + l15) * 64 + rc);
            #pragma unroll
            for (int ni = 0; ni < 4; ni++)
                bf[ni] = *(const bf16x8*)(Bl + (wn * 64 + ni * 16 + l15) * 64 + rc);
            #pragma unroll
            for (int mi = 0; mi < 4; mi++)
                #pragma unroll
                for (int ni = 0; ni < 4; ni++)
                    acc[mi][ni] = __builtin_amdgcn_mfma_f32_16x16x32_bf16(
                        af[mi], bf[ni], acc[mi][ni], 0, 0, 0);
        }
    }
}

// ============================ GEMM1: qkv projection (A=W, B=x) ============
__global__ __launch_bounds__(256) void gemm_qkv_k(
    const bf16_t* __restrict__ X, const bf16_t* __restrict__ WT,
    const float* __restrict__ bias,
    bf16_t* __restrict__ Qb, bf16_t* __restrict__ Kb, bf16_t* __restrict__ VTb)
{
    __shared__ bf16_t Al[128 * 64];
    __shared__ bf16_t Bl[128 * 64];
    const int tid = threadIdx.x;
    const int lane = tid & 63, w = tid >> 6;
    const int l15 = lane & 15, quad = lane >> 4;
    const int wm = w >> 1, wn = w & 1;
    const int n0 = blockIdx.x * 128;   // token rows
    const int m0 = blockIdx.y * 128;   // weight cols

    f32x4 acc[4][4];
    #pragma unroll
    for (int mi = 0; mi < 4; mi++)
        #pragma unroll
        for (int ni = 0; ni < 4; ni++) acc[mi][ni] = (f32x4){0.f, 0.f, 0.f, 0.f};

    gemm128_body(WT, X, Al, Bl, acc, m0, n0, 1024);

    const float QSCALE = 0.125f * LOG2E;
    const int region = m0 >> 10;  // 0:Q 1:K 2:V (uniform per block)
    #pragma unroll
    for (int mi = 0; mi < 4; mi++) {
        const int mbase = m0 + wm * 64 + mi * 16 + quad * 4;
        const float4 bia = *(const float4*)(bias + mbase);
        const float ba[4] = {bia.x, bia.y, bia.z, bia.w};
        const int col = mbase & 1023;
        const int h = col >> 6, dbase = col & 63;
        #pragma unroll
        for (int ni = 0; ni < 4; ni++) {
            const int n = n0 + wn * 64 + ni * 16 + l15;
            const int b = n >> 11, s = n & 2047;
            if (region == 0) {
                union { bf16_t bv[4]; uint2 u; } u;
                #pragma unroll
                for (int r = 0; r < 4; r++)
                    u.bv[r] = (bf16_t)((acc[mi][ni][r] + ba[r]) * QSCALE);
                *(uint2*)(Qb + (((size_t)b * 16 + h) * 2048 + s) * 64 + dbase) = u.u;
            } else if (region == 1) {
                union { bf16_t bv[4]; uint2 u; } u;
                #pragma unroll
                for (int r = 0; r < 4; r++)
                    u.bv[r] = (bf16_t)(acc[mi][ni][r] + ba[r]);
                *(uint2*)(Kb + (((size_t)b * 16 + h) * 2048 + s) * 64 + dbase) = u.u;
            } else {
                bf16_t* dst = VTb + (((size_t)b * 16 + h) * 64 + dbase) * 2048 + s;
                #pragma unroll
                for (int r = 0; r < 4; r++)
                    dst[(size_t)r * 2048] = (bf16_t)(acc[mi][ni][r] + ba[r]);
            }
        }
    }
}

// ============================ flash attention (S^T, 128-q blocks) ==========
// RETRY of R5 structure (audited 3x, no OOB found; R6 crash presumed infra).
// Block owns 128 q-rows (2 sub-tiles qa of 64). K/V staged once per kv-tile;
// K/V fragments read once, shared across both qa -> ds_read per MFMA halved.
// grid 1024, LPT order.
__global__ __launch_bounds__(256) void attn_k(
    const bf16_t* __restrict__ Qb, const bf16_t* __restrict__ Kb,
    const bf16_t* __restrict__ VTb, bf16_t* __restrict__ Ob)
{
    __shared__ bf16_t Kl[64 * 64];          // [kv][d], swizzled
    __shared__ bf16_t Vl[64 * 64];          // [d][kv], swizzled
    __shared__ bf16_t Pl[4][2 * 16 * 72];   // per-wave P[qa][q][kv], stride 72

    const int tid = threadIdx.x;
    const int w = tid >> 6, lane = tid & 63;
    const int l15 = lane & 15, quad = lane >> 4;
    const int idx = blockIdx.x;
    const int qt = 15 - (idx >> 6);         // longest first
    const int bh = idx & 63;
    const int b = bh >> 4, h = bh & 15;
    const int q0 = qt * 128;

    const bf16_t* Qp = Qb + (size_t)bh * 2048 * 64;
    const bf16_t* Kp = Kb + (size_t)bh * 2048 * 64;
    const bf16_t* Vp = VTb + (size_t)bh * 64 * 2048;

    const int srow = w * 16 + (lane >> 3);
    const int scol = ((lane & 7) ^ ((lane >> 3) & 7)) * 8;
    const int rc0 = (quad ^ (l15 & 7)) * 8;
    const int rc1 = ((quad + 4) ^ (l15 & 7)) * 8;

    // Q fragments (B-operand): rows q0+qa*64+w*16+l15, d-contig
    bf16x8 aq[2][2];
    #pragma unroll
    for (int qa = 0; qa < 2; qa++) {
        const size_t qrow = q0 + qa * 64 + w * 16 + l15;
        aq[qa][0] = *(const bf16x8*)(Qp + qrow * 64 + quad * 8);
        aq[qa][1] = *(const bf16x8*)(Qp + qrow * 64 + 32 + quad * 8);
    }

    bf16x8 vone;
    #pragma unroll
    for (int j = 0; j < 8; j++) vone[j] = (bf16_t)1.0f;

    f32x4 o[2][4];
    #pragma unroll
    for (int qa = 0; qa < 2; qa++)
        #pragma unroll
        for (int ni = 0; ni < 4; ni++) o[qa][ni] = (f32x4){0.f, 0.f, 0.f, 0.f};
    f32x4 lacc[2] = {(f32x4){0.f, 0.f, 0.f, 0.f}, (f32x4){0.f, 0.f, 0.f, 0.f}};
    const int qloc = w * 16 + l15;          // q offset within its 64-row sub-tile

    for (int kv0 = 0; kv0 <= q0 + 64; kv0 += 64) {
        __syncthreads();
        gld_lds16(Kp + (size_t)(kv0 + srow) * 64 + scol, Kl + (w * 16) * 64);
        gld_lds16(Kp + (size_t)(kv0 + srow + 8) * 64 + scol, Kl + (w * 16 + 8) * 64);
        gld_lds16(Vp + (size_t)srow * 2048 + kv0 + scol, Vl + (w * 16) * 64);
        gld_lds16(Vp + (size_t)(srow + 8) * 2048 + kv0 + scol, Vl + (w * 16 + 8) * 64);
        __syncthreads();

        // S^T: rows kv (quad*4+r), cols q (l15); K-frags shared across qa
        f32x4 sv[2][4];
        #pragma unroll
        for (int ni = 0; ni < 4; ni++) {
            bf16x8 ak0 = *(const bf16x8*)(Kl + (ni * 16 + l15) * 64 + rc0);
            bf16x8 ak1 = *(const bf16x8*)(Kl + (ni * 16 + l15) * 64 + rc1);
            #pragma unroll
            for (int qa = 0; qa < 2; qa++) {
                f32x4 z = (f32x4){0.f, 0.f, 0.f, 0.f};
                z = __builtin_amdgcn_mfma_f32_16x16x32_bf16(ak0, aq[qa][0], z, 0, 0, 0);
                z = __builtin_amdgcn_mfma_f32_16x16x32_bf16(ak1, aq[qa][1], z, 0, 0, 0);
                sv[qa][ni] = z;
            }
        }

        // causal mask (diagonal region only)
        if (kv0 >= q0) {
            const int qaD = (kv0 > q0) ? 1 : 0;   // sub-tile on the diagonal
            #pragma unroll
            for (int ni = 0; ni < 4; ni++)
                #pragma unroll
                for (int r = 0; r < 4; r++)
                    if (ni * 16 + quad * 4 + r > qloc) sv[qaD][ni][r] = -INFINITY;
            if (kv0 > q0) {                       // qa=0 entirely above diagonal
                #pragma unroll
                for (int ni = 0; ni < 4; ni++)
                    #pragma unroll
                    for (int r = 0; r < 4; r++) sv[0][ni][r] = -INFINITY;
            }
        }

        // p = exp2(s); pack 4 kv-adjacent -> one 8B LDS write
        #pragma unroll
        for (int qa = 0; qa < 2; qa++)
            #pragma unroll
            for (int ni = 0; ni < 4; ni++) {
                union { bf16_t bv[4]; uint2 u; } pk;
                #pragma unroll
                for (int r = 0; r < 4; r++) pk.bv[r] = (bf16_t)fexp2(sv[qa][ni][r]);
                *(uint2*)(&Pl[w][(qa * 16 + l15) * 72 + ni * 16 + quad * 4]) = pk.u;
            }
        // no barrier: Pl[w] wave-private, same-wave DS ops ordered

        bf16x8 pa[2][2];
        #pragma unroll
        for (int qa = 0; qa < 2; qa++) {
            pa[qa][0] = *(const bf16x8*)(&Pl[w][(qa * 16 + l15) * 72 + quad * 8]);
            pa[qa][1] = *(const bf16x8*)(&Pl[w][(qa * 16 + l15) * 72 + 32 + quad * 8]);
        }

        // O^T += V^T x P ; V-frags shared across qa
        #pragma unroll
        for (int ni = 0; ni < 4; ni++) {
            bf16x8 bv0 = *(const bf16x8*)(Vl + (ni * 16 + l15) * 64 + rc0);
            bf16x8 bv1 = *(const bf16x8*)(Vl + (ni * 16 + l15) * 64 + rc1);
            #pragma unroll
            for (int qa = 0; qa < 2; qa++) {
                o[qa][ni] = __builtin_amdgcn_mfma_f32_16x16x32_bf16(bv0, pa[qa][0], o[qa][ni], 0, 0, 0);
                o[qa][ni] = __builtin_amdgcn_mfma_f32_16x16x32_bf16(bv1, pa[qa][1], o[qa][ni], 0, 0, 0);
            }
        }
        #pragma unroll
        for (int qa = 0; qa < 2; qa++) {
            lacc[qa] = __builtin_amdgcn_mfma_f32_16x16x32_bf16(vone, pa[qa][0], lacc[qa], 0, 0, 0);
            lacc[qa] = __builtin_amdgcn_mfma_f32_16x16x32_bf16(vone, pa[qa][1], lacc[qa], 0, 0, 0);
        }
    }

    #pragma unroll
    for (int qa = 0; qa < 2; qa++) {
        const float inv = 1.0f / lacc[qa][0];
        const int s = q0 + qa * 64 + w * 16 + l15;
        bf16_t* obase = Ob + ((size_t)b * 2048 + s) * 1024 + h * 64;
        #pragma unroll
        for (int ni = 0; ni < 4; ni++) {
            union { bf16_t bv[4]; uint2 u; } u;
            #pragma unroll
            for (int r = 0; r < 4; r++) u.bv[r] = (bf16_t)(o[qa][ni][r] * inv);
            *(uint2*)(obase + ni * 16 + quad * 4) = u.u;
        }
    }
}

// ============================ GEMM2: output projection (light tiles) =======
// A=Wo^T (m = out col, 64-wide), B=O (n = token row, 128-wide). acc[2][4] ->
// ~32 AGPR + low VGPR: 3-4 blocks/CU (vs 2 for the 128x128 body).
// grid (64 n-tiles, 16 m-tiles) = 1024 blocks, 4 waves in 2x2.
__global__ __launch_bounds__(256) void gemm_out_k(
    const bf16_t* __restrict__ O, const bf16_t* __restrict__ WT,
    const float* __restrict__ bias, float* __restrict__ out)
{
    __shared__ bf16_t Al[64 * 64];     // W tile [m][k]
    __shared__ bf16_t Bl[128 * 64];    // O tile [n][k]
    const int tid = threadIdx.x;
    const int lane = tid & 63, w = tid >> 6;
    const int l15 = lane & 15, quad = lane >> 4;
    const int wm = w >> 1, wn = w & 1;
    const int n0 = blockIdx.x * 128;   // token rows
    const int m0 = blockIdx.y * 64;    // out cols

    const int srow = lane >> 3;
    const int scg = ((lane & 7) ^ srow) * 8;
    const bf16_t* Ag = WT + (size_t)(m0 + w * 16 + srow) * 1024 + scg;
    const bf16_t* Bg = O + (size_t)(n0 + w * 32 + srow) * 1024 + scg;
    bf16_t* Ald = Al + (w * 16) * 64;
    bf16_t* Bld = Bl + (w * 32) * 64;

    const int rc0 = (quad ^ (l15 & 7)) * 8;
    const int rc1 = ((quad + 4) ^ (l15 & 7)) * 8;

    f32x4 acc[2][4];
    #pragma unroll
    for (int mi = 0; mi < 2; mi++)
        #pragma unroll
        for (int ni = 0; ni < 4; ni++) acc[mi][ni] = (f32x4){0.f, 0.f, 0.f, 0.f};

    for (int k0 = 0; k0 < 1024; k0 += 64) {
        __syncthreads();
        gld_lds16(Ag + k0, Ald);
        gld_lds16(Ag + k0 + (size_t)8 * 1024, Ald + 8 * 64);
        #pragma unroll
        for (int j = 0; j < 4; j++)
            gld_lds16(Bg + k0 + (size_t)(j * 8) * 1024, Bld + (j * 8) * 64);
        __syncthreads();

        #pragma unroll
        for (int hh = 0; hh < 2; hh++) {
            const int rc = hh ? rc1 : rc0;
            bf16x8 af[2], bf[4];
            #pragma unroll
            for (int mi = 0; mi < 2; mi++)
                af[mi] = *(const bf16x8*)(Al + (wm * 32 + mi * 16 + l15) * 64 + rc);
            #pragma unroll
            for (int ni = 0; ni < 4; ni++)
                bf[ni] = *(const bf16x8*)(Bl + (wn * 64 + ni * 16 + l15) * 64 + rc);
            #pragma unroll
            for (int mi = 0; mi < 2; mi++)
                #pragma unroll
                for (int ni = 0; ni < 4; ni++)
                    acc[mi][ni] = __builtin_amdgcn_mfma_f32_16x16x32_bf16(
                        af[mi], bf[ni], acc[mi][ni], 0, 0, 0);
        }
    }

    #pragma unroll
    for (int mi = 0; mi < 2; mi++) {
        const int mbase = m0 + wm * 32 + mi * 16 + quad * 4;
        const float4 bia = *(const float4*)(bias + mbase);
        #pragma unroll
        for (int ni = 0; ni < 4; ni++) {
            const int n = n0 + wn * 64 + ni * 16 + l15;
            float4 v;
            v.x = acc[mi][ni][0] + bia.x;
            v.y = acc[mi][ni][1] + bia.y;
            v.z = acc[mi][ni][2] + bia.z;
            v.w = acc[mi][ni][3] + bia.w;
            *(float4*)(out + (size_t)n * 1024 + mbase) = v;
        }
    }
}

// ============================ launcher ============================

extern "C" void kernel_launch(void* const* d_in, const int* in_sizes, int n_in,
                              void* d_out, int out_size, void* d_ws, size_t ws_size,
                              hipStream_t stream) {
    const float* x     = (const float*)d_in[0];
    const float* W_qkv = (const float*)d_in[1];
    const float* b_qkv = (const float*)d_in[2];
    const float* W_o   = (const float*)d_in[3];
    const float* b_o   = (const float*)d_in[4];
    float* out = (float*)d_out;

    char* ws = (char*)d_ws;
    size_t off = 0;
    auto alloc = [&](size_t bytes) -> void* {
        void* p = ws + off;
        off += (bytes + 255) & ~(size_t)255;
        return p;
    };
    bf16_t* xb    = (bf16_t*)alloc((size_t)8192 * 1024 * 2);
    bf16_t* wqkvT = (bf16_t*)alloc((size_t)3072 * 1024 * 2);
    bf16_t* woT   = (bf16_t*)alloc((size_t)1024 * 1024 * 2);
    bf16_t* Qb    = (bf16_t*)alloc((size_t)8192 * 1024 * 2);
    bf16_t* Kb    = (bf16_t*)alloc((size_t)8192 * 1024 * 2);
    bf16_t* VTb   = (bf16_t*)alloc((size_t)8192 * 1024 * 2);
    bf16_t* Ob    = xb;  // xb dead after gemm_qkv_k

    prep_k<<<12288, 256, 0, stream>>>(x, xb, W_qkv, wqkvT, W_o, woT);
    gemm_qkv_k<<<dim3(64, 24), 256, 0, stream>>>(xb, wqkvT, b_qkv, Qb, Kb, VTb);
    attn_k<<<1024, 256, 0, stream>>>(Qb, Kb, VTb, Ob);
    gemm_out_k<<<dim3(64, 16), 256, 0, stream>>>(Ob, woT, b_o, out);
}